// Round 7
// baseline (638.204 us; speedup 1.0000x reference)
//
#include <hip/hip_runtime.h>

// TemporalLSTM round 7 (gfx950): R6 structure + explicit VGPR budget.
// R6 post-mortem: compiler capped at 120 VGPRs (default occupancy heuristic) and
// spilled ~70 regs of weight/acc state to scratch INSIDE the step loop ->
// WRITE_SIZE 680 MB, HBM-bound at 1.24 TB/s, 611 us. Peak live state is ~190
// VGPRs (96 weight frags + 32 acc + 32 xn + h/c state). __launch_bounds__(64, 2)
// = min 2 waves/EU -> 256-VGPR cap, which is exactly the occupancy this design
// targets (2048 single-wave blocks = 8 waves/CU = 2/SIMD). No other changes.
//
// Structure recap (R5/R6): A = weights (resident VGPR frags), B = activations.
// Gate-row permutation  tile t8 = hb*4+g :  row m -> R = 32g + 8*(m>>2) + 4*hb + (m&3)
// gives C/D (m=4q+r, n): acc[hb*4+g][r] = gate g, batch col n, j = 8q+4hb+r.
// Blocks own 8 batches; C/D columns n and n+8 duplicate batch n&7. Lane (n16,q)
// does pointwise only for half = n16>>3 (4 cells/lane, 40 trans/wave-step);
// partner lane n16^8 supplies the other 4 h values via __shfl_xor. The h
// recurrence lives entirely in VGPRs - no LDS round-trip, no step barriers.
//
// Numerics identical to R2-R6: split-bf16 (hi + residual lo) GEMM keeping
// Whi*Bhi + Whi*Blo + Wlo*Bhi (fp32 acc), x-proj + bias in one K<=17 mfma
// (k0-4 xh*Wih_hi | k5-9 xl*Wih_hi | k10-14 xh*Wih_lo | k15 1*bias_hi |
//  k16 (quad2) 1*bias_lo), exp2/rcp sigmoid+tanh.

typedef __bf16 bf16x8 __attribute__((ext_vector_type(8)));
typedef float  f32x4  __attribute__((ext_vector_type(4)));
typedef unsigned int u32;

constexpr int kT = 200, kIN = 5, kH = 32;
constexpr int CT = 40;   // timesteps of x staged per phase (200 = 5*40)

union FragU { bf16x8 v; __bf16 b[8]; unsigned short s[8]; u32 u[4]; uint4 q4; };

__device__ __forceinline__ unsigned short bfbits(__bf16 b) {
    union { __bf16 b; unsigned short s; } u; u.b = b; return u.s;
}
__device__ __forceinline__ void split2(float x, __bf16& hi, __bf16& lo) {
    hi = (__bf16)x;                 // RNE cvt
    lo = (__bf16)(x - (float)hi);   // residual, |lo| <= 2^-9 |x|
}
__device__ __forceinline__ float sigm(float z) {
    return __builtin_amdgcn_rcpf(1.0f + __builtin_amdgcn_exp2f(-1.4426950408889634f * z));
}
__device__ __forceinline__ float tanhv(float z) {
    return fmaf(2.0f,
        __builtin_amdgcn_rcpf(1.0f + __builtin_amdgcn_exp2f(-2.8853900817779268f * z)),
        -1.0f);
}

__global__ __launch_bounds__(64, 2) void lstm_reg3(
    const float* __restrict__ x,     // [B,200,5]
    const float* __restrict__ W_ih,  // [128,5]
    const float* __restrict__ W_hh,  // [128,32]
    const float* __restrict__ b_ih,  // [128]
    const float* __restrict__ b_hh,  // [128]
    const float* __restrict__ W_fc,  // [2,32]
    const float* __restrict__ b_fc,  // [2]
    float* __restrict__ out)         // [B,2]
{
    __shared__ uint4 xbuf[CT][18];   // cols 0..15: x B-frags (8 batches x 2 quads);
                                     // col 16: k16 one-quad, col 17: zero quad

    const int lane = threadIdx.x;    // single-wave block
    const int n16  = lane & 15;
    const int q    = lane >> 4;
    const int half = n16 >> 3;       // which 4-j group this lane's pointwise owns
    const int bb   = n16 & 7;        // batch within block
    const int b0   = blockIdx.x * 8;

    // ---- weight A-frags resident in VGPRs (A[m][k]: m = lane&15, k = q*8+j) ----
    bf16x8 whhA_h[8], whhA_l[8], wihA[8];
#pragma unroll
    for (int t8 = 0; t8 < 8; ++t8) {
        const int g  = t8 & 3, hb = t8 >> 2;
        const int R  = g * 32 + 8 * (n16 >> 2) + 4 * hb + (n16 & 3);  // gate row
        FragU H, L;
#pragma unroll
        for (int j = 0; j < 8; ++j)
            split2(W_hh[R * kH + q * 8 + j], H.b[j], L.b[j]);
        whhA_h[t8] = H.v; whhA_l[t8] = L.v;

        float wr[5];
#pragma unroll
        for (int i = 0; i < 5; ++i) wr[i] = W_ih[R * kIN + i];
        __bf16 bh, bl;
        split2(b_ih[R] + b_hh[R], bh, bl);

        FragU F;
        F.u[0] = F.u[1] = F.u[2] = F.u[3] = 0u;
        if (q == 0) {                       // k0..7
#pragma unroll
            for (int i = 0; i < 5; ++i) F.b[i] = (__bf16)wr[i];       // k0..4: Wih_hi
#pragma unroll
            for (int i = 0; i < 3; ++i) F.b[5 + i] = (__bf16)wr[i];   // k5..7: Wih_hi(0..2)
        } else if (q == 1) {                // k8..15
            F.b[0] = (__bf16)wr[3];                                   // k8:  Wih_hi(3)
            F.b[1] = (__bf16)wr[4];                                   // k9:  Wih_hi(4)
#pragma unroll
            for (int i = 0; i < 5; ++i) {                             // k10..14: Wih_lo
                __bf16 hbb, lbb; split2(wr[i], hbb, lbb);
                F.b[2 + i] = lbb;
            }
            F.b[7] = bh;                                              // k15: bias_hi
        } else if (q == 2) {
            F.b[0] = bl;                                              // k16: bias_lo
        }
        wihA[t8] = F.v;
    }

    // ---- const x-frag quads (written once) ----
    for (int t2 = lane; t2 < CT; t2 += 64) {
        xbuf[t2][16] = make_uint4(0x3F80u, 0u, 0u, 0u);   // quad2: k16 B=1.0 (bf16)
        xbuf[t2][17] = make_uint4(0u, 0u, 0u, 0u);        // quad3: zeros
    }

    const int col = (q < 2) ? (bb * 2 + q) : (14 + q);    // loop-invariant frag column
    const f32x4 zf4 = {0.f, 0.f, 0.f, 0.f};

    // recurrence state, in registers: this lane's 4 cells (batch bb, j = 8q+4*half+r)
    float c4s[4] = {0.f, 0.f, 0.f, 0.f};
    float hf[4]  = {0.f, 0.f, 0.f, 0.f};
    FragU Bh, Bl;                          // assembled h B-frags (own + partner)
    Bh.u[0] = Bh.u[1] = Bh.u[2] = Bh.u[3] = 0u;
    Bl.u[0] = Bl.u[1] = Bl.u[2] = Bl.u[3] = 0u;

    f32x4 xn[8];                           // pipelined x-proj + bias

    for (int phase = 0; phase < kT / CT; ++phase) {
        // ---- stage CT steps of x as ready-made B-frags (64 lanes, 8 batches) ----
        {
            const int mm = lane >> 3, pp = lane & 7;      // batch row, 5-step chunk
            const float* xrow = x + (size_t)(b0 + mm) * (kT * kIN)
                                  + (size_t)(phase * CT + pp * 5) * kIN;
            float xv[25];
#pragma unroll
            for (int i = 0; i < 25; ++i) xv[i] = xrow[i];
#pragma unroll
            for (int s5 = 0; s5 < 5; ++s5) {
                u32 xh[5], xl[5];
#pragma unroll
                for (int i = 0; i < 5; ++i) {
                    __bf16 hbb, lbb; split2(xv[s5 * 5 + i], hbb, lbb);
                    xh[i] = bfbits(hbb); xl[i] = bfbits(lbb);
                }
                uint4 f0 = make_uint4(xh[0] | (xh[1] << 16),
                                      xh[2] | (xh[3] << 16),
                                      xh[4] | (xl[0] << 16),
                                      xl[1] | (xl[2] << 16));
                uint4 f1 = make_uint4(xl[3] | (xl[4] << 16),
                                      xh[0] | (xh[1] << 16),
                                      xh[2] | (xh[3] << 16),
                                      xh[4] | (0x3F80u << 16));   // k15: B = 1.0
                const int tc = pp * 5 + s5;
                xbuf[tc][mm * 2 + 0] = f0;
                xbuf[tc][mm * 2 + 1] = f1;
            }
        }
        __syncthreads();   // single-wave block: lgkmcnt drain

        // x-proj for the first step of this phase
        {
            FragU xg; xg.q4 = xbuf[0][col];
#pragma unroll
            for (int t8 = 0; t8 < 8; ++t8)
                xn[t8] = __builtin_amdgcn_mfma_f32_16x16x32_bf16(wihA[t8], xg.v, zf4, 0, 0, 0);
        }

#pragma unroll 1
        for (int tc = 0; tc < CT; ++tc) {
            // h-dependent GEMM: 3 mfma per tile, acc init = precomputed x-proj+bias
            f32x4 acc[8];
#pragma unroll
            for (int t8 = 0; t8 < 8; ++t8) {
                f32x4 a = __builtin_amdgcn_mfma_f32_16x16x32_bf16(whhA_h[t8], Bh.v, xn[t8], 0, 0, 0);
                a = __builtin_amdgcn_mfma_f32_16x16x32_bf16(whhA_h[t8], Bl.v, a, 0, 0, 0);
                a = __builtin_amdgcn_mfma_f32_16x16x32_bf16(whhA_l[t8], Bh.v, a, 0, 0, 0);
                acc[t8] = a;
            }

            // prefetch next step's x-proj (h-independent)
            {
                const int tn = (tc + 1 < CT) ? tc + 1 : 0;
                FragU xg; xg.q4 = xbuf[tn][col];
#pragma unroll
                for (int t8 = 0; t8 < 8; ++t8)
                    xn[t8] = __builtin_amdgcn_mfma_f32_16x16x32_bf16(wihA[t8], xg.v, zf4, 0, 0, 0);
            }

            // select this lane's half of the accs (4 gates x 4 cells)
            f32x4 av[4];
#pragma unroll
            for (int g = 0; g < 4; ++g) av[g] = half ? acc[4 + g] : acc[g];

            // pointwise: 4 cells/lane (batch bb, j = 8q + 4*half + r)
            u32 ph[4], pl[4];
#pragma unroll
            for (int r = 0; r < 4; ++r) {
                float iv = sigm (av[0][r]);
                float fv = sigm (av[1][r]);
                float gv = tanhv(av[2][r]);
                float ov = sigm (av[3][r]);
                float cn = fmaf(fv, c4s[r], iv * gv);
                c4s[r] = cn;
                float hn = ov * tanhv(cn);
                hf[r] = hn;
                __bf16 hh, hl;
                split2(hn, hh, hl);
                ph[r] = bfbits(hh); pl[r] = bfbits(hl);
            }
            // pack own 4 cells: (r0,r1) and (r2,r3)
            u32 oh0 = ph[0] | (ph[1] << 16), oh1 = ph[2] | (ph[3] << 16);
            u32 ol0 = pl[0] | (pl[1] << 16), ol1 = pl[2] | (pl[3] << 16);
            // exchange with partner lane (n16 ^ 8): other 4 h of this column
            u32 sh0 = (u32)__shfl_xor((int)oh0, 8);
            u32 sh1 = (u32)__shfl_xor((int)oh1, 8);
            u32 sl0 = (u32)__shfl_xor((int)ol0, 8);
            u32 sl1 = (u32)__shfl_xor((int)ol1, 8);
            // B-frag kk0..3 = half-0 cells, kk4..7 = half-1 cells
            Bh.u[0] = half ? sh0 : oh0;
            Bh.u[1] = half ? sh1 : oh1;
            Bh.u[2] = half ? oh0 : sh0;
            Bh.u[3] = half ? oh1 : sh1;
            Bl.u[0] = half ? sl0 : ol0;
            Bl.u[1] = half ? sl1 : ol1;
            Bl.u[2] = half ? ol0 : sl0;
            Bl.u[3] = half ? ol1 : sl1;
        }
    }

    // ---- epilogue: every lane holds 4 distinct final h values ----
    // h[batch bb][j = 8q + 4*half + r] = hf[r]
    __syncthreads();
    float* hfin = (float*)xbuf;            // reuse LDS: [8][33] f32
#pragma unroll
    for (int r = 0; r < 4; ++r)
        hfin[bb * 33 + q * 8 + 4 * half + r] = hf[r];
    __syncthreads();
    if (lane < 16) {
        const int m = lane >> 1, o = lane & 1;
        float s = b_fc[o];
#pragma unroll
        for (int j = 0; j < kH; ++j)
            s = fmaf(hfin[m * 33 + j], W_fc[o * kH + j], s);
        out[(size_t)(b0 + m) * 2 + o] = s;
    }
}

extern "C" void kernel_launch(void* const* d_in, const int* in_sizes, int n_in,
                              void* d_out, int out_size, void* d_ws, size_t ws_size,
                              hipStream_t stream) {
    const float* x    = (const float*)d_in[0];
    const float* W_ih = (const float*)d_in[1];
    const float* W_hh = (const float*)d_in[2];
    const float* b_ih = (const float*)d_in[3];
    const float* b_hh = (const float*)d_in[4];
    const float* W_fc = (const float*)d_in[5];
    const float* b_fc = (const float*)d_in[6];
    float* out = (float*)d_out;

    // 16384 batches / 8 per wave = 2048 single-wave blocks (2 waves/SIMD)
    hipLaunchKernelGGL(lstm_reg3, dim3(2048), dim3(64), 0, stream,
                       x, W_ih, W_hh, b_ih, b_hh, W_fc, b_fc, out);
}

// Round 8
// 329.791 us; speedup vs baseline: 1.9352x; 1.9352x over previous
//
#include <hip/hip_runtime.h>

// TemporalLSTM round 8 (gfx950): R6 structure, spill fixed by deleting the
// xn[8] prefetch array (-32 loop-carried VGPRs) and hf[4] (-4).
//
// R7 post-mortem: launch_bounds(64,2) did NOT stop the spill (VGPR 84, WRITE
// 545 MB, 609 us) -> allocator refuses this working set regardless of cap.
// R5's loop (no av/pack extras) fit at 136 VGPR spill-free. Fix: the x-proj
// mfma depends only on xg (LDS), not on h -> no software prefetch needed;
// fuse it as the first mfma of each tile chain. h-critical path unchanged.
//
// Structure recap: A = weights (resident VGPR frags), B = activations.
// Gate-row permutation  tile t8 = hb*4+g :  row m -> R = 32g + 8*(m>>2) + 4*hb + (m&3)
// gives C/D (m=4q+r, n): acc[hb*4+g][r] = gate g, batch col n, j = 8q+4hb+r.
// Blocks own 8 batches; C/D columns n and n+8 duplicate batch n&7. Lane (n16,q)
// does pointwise only for half = n16>>3 (4 cells/lane, 40 trans/wave-step);
// partner lane n16^8 supplies the other 4 h values via __shfl_xor. The h
// recurrence lives entirely in VGPRs - no LDS round-trip, no step barriers.
// 2048 single-wave blocks = 2 independent waves/SIMD.
//
// Numerics identical to R2-R7: split-bf16 (hi + residual lo) GEMM keeping
// Whi*Bhi + Whi*Blo + Wlo*Bhi (fp32 acc), x-proj + bias in one K<=17 mfma
// (k0-4 xh*Wih_hi | k5-9 xl*Wih_hi | k10-14 xh*Wih_lo | k15 1*bias_hi |
//  k16 (quad2) 1*bias_lo), exp2/rcp sigmoid+tanh.

typedef __bf16 bf16x8 __attribute__((ext_vector_type(8)));
typedef float  f32x4  __attribute__((ext_vector_type(4)));
typedef unsigned int u32;

constexpr int kT = 200, kIN = 5, kH = 32;
constexpr int CT = 40;   // timesteps of x staged per phase (200 = 5*40)

union FragU { bf16x8 v; __bf16 b[8]; unsigned short s[8]; u32 u[4]; uint4 q4; };

__device__ __forceinline__ unsigned short bfbits(__bf16 b) {
    union { __bf16 b; unsigned short s; } u; u.b = b; return u.s;
}
__device__ __forceinline__ float bf16f(u32 low16bits) {
    return __uint_as_float(low16bits << 16);
}
__device__ __forceinline__ void split2(float x, __bf16& hi, __bf16& lo) {
    hi = (__bf16)x;                 // RNE cvt
    lo = (__bf16)(x - (float)hi);   // residual, |lo| <= 2^-9 |x|
}
__device__ __forceinline__ float sigm(float z) {
    return __builtin_amdgcn_rcpf(1.0f + __builtin_amdgcn_exp2f(-1.4426950408889634f * z));
}
__device__ __forceinline__ float tanhv(float z) {
    return fmaf(2.0f,
        __builtin_amdgcn_rcpf(1.0f + __builtin_amdgcn_exp2f(-2.8853900817779268f * z)),
        -1.0f);
}

__global__ __launch_bounds__(64) void lstm_reg4(
    const float* __restrict__ x,     // [B,200,5]
    const float* __restrict__ W_ih,  // [128,5]
    const float* __restrict__ W_hh,  // [128,32]
    const float* __restrict__ b_ih,  // [128]
    const float* __restrict__ b_hh,  // [128]
    const float* __restrict__ W_fc,  // [2,32]
    const float* __restrict__ b_fc,  // [2]
    float* __restrict__ out)         // [B,2]
{
    __shared__ uint4 xbuf[CT][18];   // cols 0..15: x B-frags (8 batches x 2 quads);
                                     // col 16: k16 one-quad, col 17: zero quad

    const int lane = threadIdx.x;    // single-wave block
    const int n16  = lane & 15;
    const int q    = lane >> 4;
    const int half = n16 >> 3;       // which 4-j group this lane's pointwise owns
    const int bb   = n16 & 7;        // batch within block
    const int b0   = blockIdx.x * 8;

    // ---- weight A-frags resident in VGPRs (A[m][k]: m = lane&15, k = q*8+j) ----
    bf16x8 whhA_h[8], whhA_l[8], wihA[8];
#pragma unroll
    for (int t8 = 0; t8 < 8; ++t8) {
        const int g  = t8 & 3, hb = t8 >> 2;
        const int R  = g * 32 + 8 * (n16 >> 2) + 4 * hb + (n16 & 3);  // gate row
        FragU H, L;
#pragma unroll
        for (int j = 0; j < 8; ++j)
            split2(W_hh[R * kH + q * 8 + j], H.b[j], L.b[j]);
        whhA_h[t8] = H.v; whhA_l[t8] = L.v;

        float wr[5];
#pragma unroll
        for (int i = 0; i < 5; ++i) wr[i] = W_ih[R * kIN + i];
        __bf16 bh, bl;
        split2(b_ih[R] + b_hh[R], bh, bl);

        FragU F;
        F.u[0] = F.u[1] = F.u[2] = F.u[3] = 0u;
        if (q == 0) {                       // k0..7
#pragma unroll
            for (int i = 0; i < 5; ++i) F.b[i] = (__bf16)wr[i];       // k0..4: Wih_hi
#pragma unroll
            for (int i = 0; i < 3; ++i) F.b[5 + i] = (__bf16)wr[i];   // k5..7: Wih_hi(0..2)
        } else if (q == 1) {                // k8..15
            F.b[0] = (__bf16)wr[3];                                   // k8:  Wih_hi(3)
            F.b[1] = (__bf16)wr[4];                                   // k9:  Wih_hi(4)
#pragma unroll
            for (int i = 0; i < 5; ++i) {                             // k10..14: Wih_lo
                __bf16 hbb, lbb; split2(wr[i], hbb, lbb);
                F.b[2 + i] = lbb;
            }
            F.b[7] = bh;                                              // k15: bias_hi
        } else if (q == 2) {
            F.b[0] = bl;                                              // k16: bias_lo
        }
        wihA[t8] = F.v;
    }

    // ---- const x-frag quads (written once) ----
    for (int t2 = lane; t2 < CT; t2 += 64) {
        xbuf[t2][16] = make_uint4(0x3F80u, 0u, 0u, 0u);   // quad2: k16 B=1.0 (bf16)
        xbuf[t2][17] = make_uint4(0u, 0u, 0u, 0u);        // quad3: zeros
    }

    const int col = (q < 2) ? (bb * 2 + q) : (14 + q);    // loop-invariant frag column
    const f32x4 zf4 = {0.f, 0.f, 0.f, 0.f};

    // recurrence state, in registers: this lane's 4 cells (batch bb, j = 8q+4*half+r)
    float c4s[4] = {0.f, 0.f, 0.f, 0.f};
    FragU Bh, Bl;                          // assembled h B-frags (own + partner)
    Bh.u[0] = Bh.u[1] = Bh.u[2] = Bh.u[3] = 0u;
    Bl.u[0] = Bl.u[1] = Bl.u[2] = Bl.u[3] = 0u;

    for (int phase = 0; phase < kT / CT; ++phase) {
        // ---- stage CT steps of x as ready-made B-frags (64 lanes, 8 batches) ----
        {
            const int mm = lane >> 3, pp = lane & 7;      // batch row, 5-step chunk
            const float* xrow = x + (size_t)(b0 + mm) * (kT * kIN)
                                  + (size_t)(phase * CT + pp * 5) * kIN;
            float xv[25];
#pragma unroll
            for (int i = 0; i < 25; ++i) xv[i] = xrow[i];
#pragma unroll
            for (int s5 = 0; s5 < 5; ++s5) {
                u32 xh[5], xl[5];
#pragma unroll
                for (int i = 0; i < 5; ++i) {
                    __bf16 hbb, lbb; split2(xv[s5 * 5 + i], hbb, lbb);
                    xh[i] = bfbits(hbb); xl[i] = bfbits(lbb);
                }
                uint4 f0 = make_uint4(xh[0] | (xh[1] << 16),
                                      xh[2] | (xh[3] << 16),
                                      xh[4] | (xl[0] << 16),
                                      xl[1] | (xl[2] << 16));
                uint4 f1 = make_uint4(xl[3] | (xl[4] << 16),
                                      xh[0] | (xh[1] << 16),
                                      xh[2] | (xh[3] << 16),
                                      xh[4] | (0x3F80u << 16));   // k15: B = 1.0
                const int tc = pp * 5 + s5;
                xbuf[tc][mm * 2 + 0] = f0;
                xbuf[tc][mm * 2 + 1] = f1;
            }
        }
        __syncthreads();   // single-wave block: lgkmcnt drain

#pragma unroll 1
        for (int tc = 0; tc < CT; ++tc) {
            FragU xg; xg.q4 = xbuf[tc][col];

            // per tile: x-proj+bias (h-independent, scheduler hoists it) then
            // the 3-mfma h chain. No xn prefetch array -> 32 fewer live VGPRs.
            f32x4 acc[8];
#pragma unroll
            for (int t8 = 0; t8 < 8; ++t8) {
                f32x4 a = __builtin_amdgcn_mfma_f32_16x16x32_bf16(wihA[t8], xg.v, zf4, 0, 0, 0);
                a = __builtin_amdgcn_mfma_f32_16x16x32_bf16(whhA_h[t8], Bh.v, a, 0, 0, 0);
                a = __builtin_amdgcn_mfma_f32_16x16x32_bf16(whhA_h[t8], Bl.v, a, 0, 0, 0);
                a = __builtin_amdgcn_mfma_f32_16x16x32_bf16(whhA_l[t8], Bh.v, a, 0, 0, 0);
                acc[t8] = a;
            }

            // pointwise: 4 cells/lane (batch bb, j = 8q + 4*half + r)
            u32 ph[4], pl[4];
#pragma unroll
            for (int r = 0; r < 4; ++r) {
                float pi = half ? acc[4][r] : acc[0][r];
                float pf = half ? acc[5][r] : acc[1][r];
                float pg = half ? acc[6][r] : acc[2][r];
                float po = half ? acc[7][r] : acc[3][r];
                float iv = sigm (pi);
                float fv = sigm (pf);
                float gv = tanhv(pg);
                float ov = sigm (po);
                float cn = fmaf(fv, c4s[r], iv * gv);
                c4s[r] = cn;
                float hn = ov * tanhv(cn);
                __bf16 hh, hl;
                split2(hn, hh, hl);
                ph[r] = bfbits(hh); pl[r] = bfbits(hl);
            }
            // pack own 4 cells: (r0,r1) and (r2,r3)
            u32 oh0 = ph[0] | (ph[1] << 16), oh1 = ph[2] | (ph[3] << 16);
            u32 ol0 = pl[0] | (pl[1] << 16), ol1 = pl[2] | (pl[3] << 16);
            // exchange with partner lane (n16 ^ 8): other 4 h of this column
            u32 sh0 = (u32)__shfl_xor((int)oh0, 8);
            u32 sh1 = (u32)__shfl_xor((int)oh1, 8);
            u32 sl0 = (u32)__shfl_xor((int)ol0, 8);
            u32 sl1 = (u32)__shfl_xor((int)ol1, 8);
            // B-frag kk0..3 = half-0 cells, kk4..7 = half-1 cells
            Bh.u[0] = half ? sh0 : oh0;
            Bh.u[1] = half ? sh1 : oh1;
            Bh.u[2] = half ? oh0 : sh0;
            Bh.u[3] = half ? oh1 : sh1;
            Bl.u[0] = half ? sl0 : ol0;
            Bl.u[1] = half ? sl1 : ol1;
            Bl.u[2] = half ? ol0 : sl0;
            Bl.u[3] = half ? ol1 : sl1;
        }
    }

    // ---- epilogue: reconstruct this lane's 4 final h from Bh/Bl (hi+lo, ~2^-17) ----
    __syncthreads();
    float* hfin = (float*)xbuf;            // reuse LDS: [8][33] f32
    {
        u32 wh0 = half ? Bh.u[2] : Bh.u[0];
        u32 wh1 = half ? Bh.u[3] : Bh.u[1];
        u32 wl0 = half ? Bl.u[2] : Bl.u[0];
        u32 wl1 = half ? Bl.u[3] : Bl.u[1];
        const int base = bb * 33 + q * 8 + 4 * half;
        hfin[base + 0] = bf16f(wh0 & 0xFFFFu) + bf16f(wl0 & 0xFFFFu);
        hfin[base + 1] = bf16f(wh0 >> 16)     + bf16f(wl0 >> 16);
        hfin[base + 2] = bf16f(wh1 & 0xFFFFu) + bf16f(wl1 & 0xFFFFu);
        hfin[base + 3] = bf16f(wh1 >> 16)     + bf16f(wl1 >> 16);
    }
    __syncthreads();
    if (lane < 16) {
        const int m = lane >> 1, o = lane & 1;
        float s = b_fc[o];
#pragma unroll
        for (int j = 0; j < kH; ++j)
            s = fmaf(hfin[m * 33 + j], W_fc[o * kH + j], s);
        out[(size_t)(b0 + m) * 2 + o] = s;
    }
}

extern "C" void kernel_launch(void* const* d_in, const int* in_sizes, int n_in,
                              void* d_out, int out_size, void* d_ws, size_t ws_size,
                              hipStream_t stream) {
    const float* x    = (const float*)d_in[0];
    const float* W_ih = (const float*)d_in[1];
    const float* W_hh = (const float*)d_in[2];
    const float* b_ih = (const float*)d_in[3];
    const float* b_hh = (const float*)d_in[4];
    const float* W_fc = (const float*)d_in[5];
    const float* b_fc = (const float*)d_in[6];
    float* out = (float*)d_out;

    // 16384 batches / 8 per wave = 2048 single-wave blocks (2 waves/SIMD)
    hipLaunchKernelGGL(lstm_reg4, dim3(2048), dim3(64), 0, stream,
                       x, W_ih, W_hh, b_ih, b_hh, W_fc, b_fc, out);
}

// Round 9
// 243.903 us; speedup vs baseline: 2.6166x; 1.3521x over previous
//
#include <hip/hip_runtime.h>

// TemporalLSTM round 9 (gfx950): R5 16-batch/wave in-register recurrence +
// transcendental reduction + cheap xg prefetch.
//
// R8 post-mortem: 8-batch/wave (2 waves/SIMD) regressed vs R5 (282 vs 216 us):
// doubled mfma + select/shfl overhead, and phase-locked waves don't hide each
// other's trans stalls. R5's shape is right; the cost is trans ops (80/wave-step
// x ~16cyc ~= 1280 of 1790 busy cyc) + exposed ds_read latency.
//
// R9 deltas (math value-identical, fewer trans):
//  - weights pre-scaled by log2e (2*log2e for g-gate rows); c kept in 2L units
//    -> every exp2 arg is a raw acc value (free neg modifier), no arg muls.
//  - fused products: i*g = (1-v)/[(1+u)(1+v)], o*tanh(c) = (1-s)/[(1+p)(1+s)],
//    f*c = c*invB  -> 8 trans/cell; rcps paired across adjacent cells -> 6.5.
//    c clamped at -35 (tanh==-1 to 2e-11 there) so paired C can't overflow f32.
//  - xg-only prefetch (4 VGPRs, not R5's spill-prone xn[8]); hf[] dropped
//    (epilogue reconstructs h from Bh/Bl hi+lo).
//
// Structure recap (verified R5): A = weights (resident VGPR frags), B = h.
// Gate-row permutation  tile t8 = hb*4+g :  row m -> R = 32g + 8*(m>>2) + 4*hb + (m&3)
// gives C/D (m=4q+r, n): acc[hb*4+g][r] = gate g, batch col n, j = 8q+4hb+r,
// and the next-step B-frag (B[k][n], k=8q+kk -> h[n][8q+kk]) is the lane's own
// pointwise output. No LDS round-trip, no step barriers. 1024 single-wave blocks.

typedef __bf16 bf16x8 __attribute__((ext_vector_type(8)));
typedef float  f32x4  __attribute__((ext_vector_type(4)));
typedef unsigned int u32;

constexpr int kT = 200, kIN = 5, kH = 32;
constexpr int CT = 40;   // timesteps of x staged per phase (200 = 5*40)

constexpr float kL  = 1.4426950408889634f;   // log2(e)
constexpr float k2L = 2.8853900817779268f;   // 2*log2(e)

union FragU { bf16x8 v; __bf16 b[8]; unsigned short s[8]; u32 u[4]; uint4 q4; };

__device__ __forceinline__ unsigned short bfbits(__bf16 b) {
    union { __bf16 b; unsigned short s; } u; u.b = b; return u.s;
}
__device__ __forceinline__ void split2(float x, __bf16& hi, __bf16& lo) {
    hi = (__bf16)x;                 // RNE cvt
    lo = (__bf16)(x - (float)hi);   // residual, |lo| <= 2^-9 |x|
}

__global__ __launch_bounds__(64) void lstm_reg5(
    const float* __restrict__ x,     // [B,200,5]
    const float* __restrict__ W_ih,  // [128,5]
    const float* __restrict__ W_hh,  // [128,32]
    const float* __restrict__ b_ih,  // [128]
    const float* __restrict__ b_hh,  // [128]
    const float* __restrict__ W_fc,  // [2,32]
    const float* __restrict__ b_fc,  // [2]
    float* __restrict__ out)         // [B,2]
{
    __shared__ uint4 xbuf[CT][34];   // cols 0..31: x B-frags; 32/33: const quads

    const int lane = threadIdx.x;    // single-wave block
    const int n16  = lane & 15;
    const int q    = lane >> 4;
    const int b0   = blockIdx.x * 16;

    // ---- weight A-frags resident in VGPRs (A[m][k]: m = lane&15, k = q*8+j) ----
    // Scaled by kL (gates i,f,o) or k2L (gate g) BEFORE the hi/lo split, so acc
    // values are exp2-ready.
    bf16x8 whhA_h[8], whhA_l[8], wihA[8];
#pragma unroll
    for (int t8 = 0; t8 < 8; ++t8) {
        const int g  = t8 & 3, hb = t8 >> 2;
        const int R  = g * 32 + 8 * (n16 >> 2) + 4 * hb + (n16 & 3);  // gate row
        const float sc = (g == 2) ? k2L : kL;
        FragU H, L;
#pragma unroll
        for (int j = 0; j < 8; ++j)
            split2(sc * W_hh[R * kH + q * 8 + j], H.b[j], L.b[j]);
        whhA_h[t8] = H.v; whhA_l[t8] = L.v;

        float wr[5];
#pragma unroll
        for (int i = 0; i < 5; ++i) wr[i] = sc * W_ih[R * kIN + i];
        __bf16 bh, bl;
        split2(sc * (b_ih[R] + b_hh[R]), bh, bl);

        FragU F;
        F.u[0] = F.u[1] = F.u[2] = F.u[3] = 0u;
        if (q == 0) {                       // k0..7
#pragma unroll
            for (int i = 0; i < 5; ++i) F.b[i] = (__bf16)wr[i];       // k0..4: Wih_hi
#pragma unroll
            for (int i = 0; i < 3; ++i) F.b[5 + i] = (__bf16)wr[i];   // k5..7: Wih_hi(0..2)
        } else if (q == 1) {                // k8..15
            F.b[0] = (__bf16)wr[3];                                   // k8:  Wih_hi(3)
            F.b[1] = (__bf16)wr[4];                                   // k9:  Wih_hi(4)
#pragma unroll
            for (int i = 0; i < 5; ++i) {                             // k10..14: Wih_lo
                __bf16 hbb, lbb; split2(wr[i], hbb, lbb);
                F.b[2 + i] = lbb;
            }
            F.b[7] = bh;                                              // k15: bias_hi
        } else if (q == 2) {
            F.b[0] = bl;                                              // k16: bias_lo
        }
        wihA[t8] = F.v;
    }

    // ---- const x-frag quads (written once) ----
    for (int t2 = lane; t2 < CT; t2 += 64) {
        xbuf[t2][32] = make_uint4(0x3F80u, 0u, 0u, 0u);   // quad2: k16 B=1.0 (bf16)
        xbuf[t2][33] = make_uint4(0u, 0u, 0u, 0u);        // quad3: zeros
    }

    const int col = (q < 2) ? (n16 * 2 + q) : (30 + q);   // loop-invariant frag column
    const f32x4 zf4 = {0.f, 0.f, 0.f, 0.f};

    // recurrence state, fully in registers. c8 is in 2L units (c_scaled = 2L*c).
    float c8[8] = {0.f, 0.f, 0.f, 0.f, 0.f, 0.f, 0.f, 0.f};
    FragU Bh, Bl;                          // h as bf16 hi/lo B-frags
    Bh.u[0] = Bh.u[1] = Bh.u[2] = Bh.u[3] = 0u;
    Bl.u[0] = Bl.u[1] = Bl.u[2] = Bl.u[3] = 0u;

    for (int phase = 0; phase < kT / CT; ++phase) {
        // ---- stage CT steps of x as ready-made B-frags (64 lanes, 16 batches) ----
        {
            const int mm = lane >> 2, pp = lane & 3;       // batch row, 10-step chunk
            const float2* xr2 = (const float2*)(x + (size_t)(b0 + mm) * (kT * kIN)
                                                  + (size_t)(phase * CT + pp * 10) * kIN);
            float xv[50];
#pragma unroll
            for (int i = 0; i < 25; ++i) {
                float2 v = xr2[i];
                xv[2 * i] = v.x; xv[2 * i + 1] = v.y;
            }
#pragma unroll
            for (int s5 = 0; s5 < 10; ++s5) {
                u32 xh[5], xl[5];
#pragma unroll
                for (int i = 0; i < 5; ++i) {
                    __bf16 hbb, lbb; split2(xv[s5 * 5 + i], hbb, lbb);
                    xh[i] = bfbits(hbb); xl[i] = bfbits(lbb);
                }
                uint4 f0 = make_uint4(xh[0] | (xh[1] << 16),
                                      xh[2] | (xh[3] << 16),
                                      xh[4] | (xl[0] << 16),
                                      xl[1] | (xl[2] << 16));
                uint4 f1 = make_uint4(xl[3] | (xl[4] << 16),
                                      xh[0] | (xh[1] << 16),
                                      xh[2] | (xh[3] << 16),
                                      xh[4] | (0x3F80u << 16));   // k15: B = 1.0
                const int tc = pp * 10 + s5;
                xbuf[tc][mm * 2 + 0] = f0;
                xbuf[tc][mm * 2 + 1] = f1;
            }
        }
        __syncthreads();

        FragU xg; xg.q4 = xbuf[0][col];

#pragma unroll 1
        for (int tc = 0; tc < CT; ++tc) {
            // prefetch next step's xg (4 VGPRs; dummy wrap at tc=CT-1, reloaded
            // fresh after the next phase's staging barrier)
            FragU xgn;
            const int tn = (tc + 1 < CT) ? tc + 1 : 0;
            xgn.q4 = xbuf[tn][col];

            // gates: x-proj+bias mfma then 3-mfma split-bf16 h chain, per tile
            f32x4 acc[8];
#pragma unroll
            for (int t8 = 0; t8 < 8; ++t8) {
                f32x4 a = __builtin_amdgcn_mfma_f32_16x16x32_bf16(wihA[t8], xg.v, zf4, 0, 0, 0);
                a = __builtin_amdgcn_mfma_f32_16x16x32_bf16(whhA_h[t8], Bh.v, a, 0, 0, 0);
                a = __builtin_amdgcn_mfma_f32_16x16x32_bf16(whhA_h[t8], Bl.v, a, 0, 0, 0);
                a = __builtin_amdgcn_mfma_f32_16x16x32_bf16(whhA_l[t8], Bh.v, a, 0, 0, 0);
                acc[t8] = a;
            }

            // pointwise, cells in pairs (rcp shared). acc values are pre-scaled:
            // i,f,o gates = L*a; g gate = 2L*a; c8 = 2L*c.
#pragma unroll
            for (int m2 = 0; m2 < 4; ++m2) {
                const int j0 = 2 * m2, j1 = j0 + 1;
                const int hb = j0 >> 2;                   // same for both cells
                const int r0 = j0 & 3, r1 = j1 & 3;
                float ai0 = acc[hb * 4 + 0][r0], af0 = acc[hb * 4 + 1][r0];
                float ag0 = acc[hb * 4 + 2][r0], ao0 = acc[hb * 4 + 3][r0];
                float ai1 = acc[hb * 4 + 0][r1], af1 = acc[hb * 4 + 1][r1];
                float ag1 = acc[hb * 4 + 2][r1], ao1 = acc[hb * 4 + 3][r1];

                float u0 = __builtin_amdgcn_exp2f(-ai0), v0 = __builtin_amdgcn_exp2f(-ag0);
                float w0 = __builtin_amdgcn_exp2f(-af0), p0 = __builtin_amdgcn_exp2f(-ao0);
                float u1 = __builtin_amdgcn_exp2f(-ai1), v1 = __builtin_amdgcn_exp2f(-ag1);
                float w1 = __builtin_amdgcn_exp2f(-af1), p1 = __builtin_amdgcn_exp2f(-ao1);

                float A0 = (1.0f + u0) * (1.0f + v0);     // i*g denominator
                float A1 = (1.0f + u1) * (1.0f + v1);
                float B0 = 1.0f + w0, B1 = 1.0f + w1;     // f denominator
                float rA = __builtin_amdgcn_rcpf(A0 * A1);
                float rB = __builtin_amdgcn_rcpf(B0 * B1);

                float t0 = fmaf(v0, -k2L, k2L);           // 2L*(1-v0)
                float t1 = fmaf(v1, -k2L, k2L);
                // c_scaled = f*c_scaled + 2L*(i*g)
                float c0 = fmaf(c8[j0], B1 * rB, t0 * (A1 * rA));
                float c1 = fmaf(c8[j1], B0 * rB, t1 * (A0 * rA));
                c0 = fmaxf(c0, -35.0f);                   // tanh==-1 to 2e-11 here;
                c1 = fmaxf(c1, -35.0f);                   // keeps paired C in f32 range
                c8[j0] = c0; c8[j1] = c1;

                float s0 = __builtin_amdgcn_exp2f(-c0);
                float s1 = __builtin_amdgcn_exp2f(-c1);
                float C0 = (1.0f + p0) * (1.0f + s0);     // o*tanh(c) denominator
                float C1 = (1.0f + p1) * (1.0f + s1);
                float rC = __builtin_amdgcn_rcpf(C0 * C1);
                float h0 = (1.0f - s0) * (C1 * rC);       // h = o*tanh(c)
                float h1 = (1.0f - s1) * (C0 * rC);

                split2(h0, Bh.b[j0], Bl.b[j0]);
                split2(h1, Bh.b[j1], Bl.b[j1]);
            }

            xg = xgn;
        }
    }

    // ---- epilogue: reconstruct h (hi+lo, ~2^-17) and apply the FC head ----
    __syncthreads();
    float* hfin = (float*)xbuf;            // reuse LDS: [16][33] f32
#pragma unroll
    for (int jj = 0; jj < 8; ++jj)
        hfin[n16 * 33 + q * 8 + jj] = (float)Bh.b[jj] + (float)Bl.b[jj];
    __syncthreads();
    if (lane < 32) {
        const int m = lane >> 1, o = lane & 1;
        float s = b_fc[o];
#pragma unroll
        for (int j = 0; j < kH; ++j)
            s = fmaf(hfin[m * 33 + j], W_fc[o * kH + j], s);
        out[(size_t)(b0 + m) * 2 + o] = s;
    }
}

extern "C" void kernel_launch(void* const* d_in, const int* in_sizes, int n_in,
                              void* d_out, int out_size, void* d_ws, size_t ws_size,
                              hipStream_t stream) {
    const float* x    = (const float*)d_in[0];
    const float* W_ih = (const float*)d_in[1];
    const float* W_hh = (const float*)d_in[2];
    const float* b_ih = (const float*)d_in[3];
    const float* b_hh = (const float*)d_in[4];
    const float* W_fc = (const float*)d_in[5];
    const float* b_fc = (const float*)d_in[6];
    float* out = (float*)d_out;

    // 16384 batches / 16 per wave = 1024 single-wave blocks
    hipLaunchKernelGGL(lstm_reg5, dim3(1024), dim3(64), 0, stream,
                       x, W_ih, W_hh, b_ih, b_hh, W_fc, b_fc, out);
}